// Round 2
// baseline (62.336 us; speedup 1.0000x reference)
//
#include <hip/hip_runtime.h>

#define NN 8
#define MM 8
#define NH1 64
#define NH2 32

__global__ __launch_bounds__(256, 2) void barrier_policy_kernel(
    const float* __restrict__ x_g,
    const float* __restrict__ W1,  const float* __restrict__ b1,
    const float* __restrict__ W21, const float* __restrict__ b21,
    const float* __restrict__ W22, const float* __restrict__ b22,
    const float* __restrict__ W31, const float* __restrict__ b31,
    const float* __restrict__ W32, const float* __restrict__ b32,
    const float* __restrict__ Amat, const float* __restrict__ Gmat,
    const float* __restrict__ mean, const float* __restrict__ std_,
    float* __restrict__ out, int B)
{
    const int row = blockIdx.x * blockDim.x + threadIdx.x;
    if (row >= B) return;

    // ---- load x (vectorized, 32B/thread) ----
    float x[NN];
    {
        const float4* xv = reinterpret_cast<const float4*>(x_g + (size_t)row * NN);
        float4 a0 = xv[0], a1 = xv[1];
        x[0] = a0.x; x[1] = a0.y; x[2] = a0.z; x[3] = a0.w;
        x[4] = a1.x; x[5] = a1.y; x[6] = a1.z; x[7] = a1.w;
    }

    // ---- un-normalized state ----
    float x0[NN];
#pragma unroll
    for (int i = 0; i < NN; ++i) x0[i] = fmaf(x[i], std_[i], mean[i]);

    // ---- layer 1: h1 = relu(x @ W1 + b1) ----
    float h1[NH1];
#pragma unroll
    for (int j = 0; j < NH1; ++j) {
        float acc = b1[j];
#pragma unroll
        for (int k = 0; k < NN; ++k) acc = fmaf(x[k], W1[k * NH1 + j], acc);
        h1[j] = fmaxf(acc, 0.0f);
    }

    // ---- layer 2: x21 = relu(h1@W21+b21), x22 = relu(h1@W22+b22) ----
    float x21[NH2], x22[NH2];
#pragma unroll
    for (int j = 0; j < NH2; ++j) { x21[j] = b21[j]; x22[j] = b22[j]; }
#pragma unroll
    for (int k = 0; k < NH1; ++k) {
        const float h = h1[k];
#pragma unroll
        for (int j = 0; j < NH2; ++j) {
            x21[j] = fmaf(h, W21[k * NH2 + j], x21[j]);
            x22[j] = fmaf(h, W22[k * NH2 + j], x22[j]);
        }
    }
#pragma unroll
    for (int j = 0; j < NH2; ++j) {
        x21[j] = fmaxf(x21[j], 0.0f);
        x22[j] = fmaxf(x22[j], 0.0f);
    }

    // ---- heads: px = x21@W31+b31 ; alphax = 4*sigmoid(x22@W32+b32) ----
    float p[MM];
#pragma unroll
    for (int j = 0; j < MM; ++j) {
        float acc = b31[j];
#pragma unroll
        for (int k = 0; k < NH2; ++k) acc = fmaf(x21[k], W31[k * MM + j], acc);
        p[j] = acc;
    }
    float s = b32[0];
#pragma unroll
    for (int k = 0; k < NH2; ++k) s = fmaf(x22[k], W32[k], s);
    const float alphax = 4.0f / (1.0f + __expf(-s));

    // ---- barrier terms ----
    float hx = 16.0f;
#pragma unroll
    for (int i = 0; i < NN; ++i) hx = fmaf(-x0[i], x0[i], hx);

    float dh[NN];
#pragma unroll
    for (int i = 0; i < NN; ++i) dh[i] = -2.0f * x0[i];

    float Lfhx = 0.0f;
#pragma unroll
    for (int i = 0; i < NN; ++i) {
        float fx = 0.0f;
#pragma unroll
        for (int k = 0; k < NN; ++k) fx = fmaf(Amat[i * NN + k], x0[k], fx);
        Lfhx = fmaf(dh[i], fx, Lfhx);
    }

    float g[MM];
#pragma unroll
    for (int j = 0; j < MM; ++j) {
        float acc = 0.0f;
#pragma unroll
        for (int i = 0; i < NN; ++i) acc = fmaf(dh[i], Gmat[i * MM + j], acc);
        g[j] = acc;
    }

    const float c0 = fmaf(alphax, hx, Lfhx);

    // ---- QP: argmin 1/2||u||^2 + p.u  s.t. -1<=u<=1, c0 + g.u >= 0 ----
    // c_of(lam) = c0 + g . clip(-p + lam*g, -1, 1)  (nondecreasing in lam)
#define C_OF(lam, cres)                                              \
    do {                                                             \
        float c_ = c0;                                               \
        _Pragma("unroll")                                            \
        for (int j_ = 0; j_ < MM; ++j_) {                            \
            float u_ = fmaf((lam), g[j_], -p[j_]);                   \
            u_ = fminf(fmaxf(u_, -1.0f), 1.0f);                      \
            c_ = fmaf(g[j_], u_, c_);                                \
        }                                                            \
        (cres) = c_;                                                 \
    } while (0)

    float c_zero;
    C_OF(0.0f, c_zero);
    const bool viol = (c_zero < 0.0f);

    // bracket lambda* in [0, hi] (ref: 40 doubling steps; early-exit is exact
    // because once c_of(hi) >= 0 the reference's where() never changes hi)
    float hi = 1.0f;
    for (int it = 0; it < 40; ++it) {
        float c;
        C_OF(hi, c);
        const bool neg = (c < 0.0f);
        if (!__any((int)neg)) break;
        hi = neg ? 2.0f * hi : hi;
    }

    // bisection (ref: 60 steps; early-exit when interval collapsed in f32 for
    // all lanes — remaining reference iterations are exact no-ops)
    float lo = 0.0f;
    for (int it = 0; it < 60; ++it) {
        const float mid = 0.5f * (lo + hi);
        const bool active = (mid != lo) && (mid != hi);
        if (!__any((int)active)) break;
        float c;
        C_OF(mid, c);
        const bool neg = (c < 0.0f);
        lo = neg ? mid : lo;
        hi = neg ? hi : mid;
    }
    const float lam_b = 0.5f * (lo + hi);

    // frozen active set -> closed-form lambda (exact KKT refinement)
    float denom = 0.0f, num = c0;
    bool lowb[MM], highb[MM];
#pragma unroll
    for (int j = 0; j < MM; ++j) {
        const float uraw = fmaf(lam_b, g[j], -p[j]);
        lowb[j]  = (uraw <= -1.0f);
        highb[j] = (uraw >= 1.0f);
        const bool freeb = !(lowb[j] || highb[j]);
        denom += freeb ? g[j] * g[j] : 0.0f;
        num   += lowb[j] ? -g[j] : (highb[j] ? g[j] : -g[j] * p[j]);
    }
    const float lam = viol ? (-num / (denom + 1e-12f)) : 0.0f;

    float uo[MM];
#pragma unroll
    for (int j = 0; j < MM; ++j) {
        const float uf = fmaf(lam, g[j], -p[j]);
        uo[j] = lowb[j] ? -1.0f : (highb[j] ? 1.0f : uf);
    }

    // ---- store (vectorized) ----
    float4* ov = reinterpret_cast<float4*>(out + (size_t)row * MM);
    ov[0] = make_float4(uo[0], uo[1], uo[2], uo[3]);
    ov[1] = make_float4(uo[4], uo[5], uo[6], uo[7]);
#undef C_OF
}

extern "C" void kernel_launch(void* const* d_in, const int* in_sizes, int n_in,
                              void* d_out, int out_size, void* d_ws, size_t ws_size,
                              hipStream_t stream) {
    const float* x    = (const float*)d_in[0];
    const float* W1   = (const float*)d_in[1];
    const float* b1   = (const float*)d_in[2];
    const float* W21  = (const float*)d_in[3];
    const float* b21  = (const float*)d_in[4];
    const float* W22  = (const float*)d_in[5];
    const float* b22  = (const float*)d_in[6];
    const float* W31  = (const float*)d_in[7];
    const float* b31  = (const float*)d_in[8];
    const float* W32  = (const float*)d_in[9];
    const float* b32  = (const float*)d_in[10];
    const float* Amat = (const float*)d_in[11];
    const float* Gmat = (const float*)d_in[12];
    const float* mean = (const float*)d_in[13];
    const float* std_ = (const float*)d_in[14];

    const int B = in_sizes[0] / NN;
    const int block = 256;
    const int grid = (B + block - 1) / block;

    barrier_policy_kernel<<<grid, block, 0, stream>>>(
        x, W1, b1, W21, b21, W22, b22, W31, b31, W32, b32,
        Amat, Gmat, mean, std_, (float*)d_out, B);
}